// Round 1
// baseline (252.295 us; speedup 1.0000x reference)
//
#include <hip/hip_runtime.h>
#include <math.h>

#define N_RES 1024
#define N_ATOMS 37
#define ATOM_CA 1
#define NBATCH 256
#define NSUM 34
// sums layout:
// 0: M = sum m
// 1-3: Sp = sum m*p
// 4-6: St = sum m*t
// 7: Qp = sum m*|p|^2
// 8: Qt = sum m*|t|^2
// 9-17: Cpt[i][j] = sum m*p_i*t_j
// 18: S2 = sum m^2
// 19-21: S2p = sum m^2*p
// 22-24: S2t = sum m^2*t
// 25-33: C2[i][j] = sum m^2*p_i*t_j

__global__ __launch_bounds__(256) void rmsd_batch_kernel(
    const float* __restrict__ pred, const float* __restrict__ truec,
    const float* __restrict__ mask, float* __restrict__ ws)
{
    const int b = blockIdx.x;
    const int tid = threadIdx.x;

    float acc[NSUM];
#pragma unroll
    for (int i = 0; i < NSUM; ++i) acc[i] = 0.f;

    const size_t resStride = (size_t)N_ATOMS * 3;
    const float* pb = pred  + (size_t)b * N_RES * resStride + ATOM_CA * 3;
    const float* tb = truec + (size_t)b * N_RES * resStride + ATOM_CA * 3;
    const float* mb = mask  + (size_t)b * N_RES * N_ATOMS + ATOM_CA;

    for (int n = tid; n < N_RES; n += 256) {
        const float m  = mb[(size_t)n * N_ATOMS];
        const float* pp = pb + (size_t)n * resStride;
        const float* tt = tb + (size_t)n * resStride;
        const float p0 = pp[0], p1 = pp[1], p2 = pp[2];
        const float t0 = tt[0], t1 = tt[1], t2 = tt[2];
        const float m2 = m * m;
        acc[0] += m;
        acc[1] += m * p0;  acc[2] += m * p1;  acc[3] += m * p2;
        acc[4] += m * t0;  acc[5] += m * t1;  acc[6] += m * t2;
        acc[7] += m * (p0*p0 + p1*p1 + p2*p2);
        acc[8] += m * (t0*t0 + t1*t1 + t2*t2);
        acc[9]  += m * p0 * t0; acc[10] += m * p0 * t1; acc[11] += m * p0 * t2;
        acc[12] += m * p1 * t0; acc[13] += m * p1 * t1; acc[14] += m * p1 * t2;
        acc[15] += m * p2 * t0; acc[16] += m * p2 * t1; acc[17] += m * p2 * t2;
        acc[18] += m2;
        acc[19] += m2 * p0; acc[20] += m2 * p1; acc[21] += m2 * p2;
        acc[22] += m2 * t0; acc[23] += m2 * t1; acc[24] += m2 * t2;
        acc[25] += m2 * p0 * t0; acc[26] += m2 * p0 * t1; acc[27] += m2 * p0 * t2;
        acc[28] += m2 * p1 * t0; acc[29] += m2 * p1 * t1; acc[30] += m2 * p1 * t2;
        acc[31] += m2 * p2 * t0; acc[32] += m2 * p2 * t1; acc[33] += m2 * p2 * t2;
    }

    // wave(64) shuffle reduce each accumulator
#pragma unroll
    for (int i = 0; i < NSUM; ++i) {
        float v = acc[i];
#pragma unroll
        for (int off = 32; off > 0; off >>= 1) v += __shfl_down(v, off, 64);
        acc[i] = v;
    }

    __shared__ float partial[4][NSUM];
    __shared__ double sums[NSUM];
    const int wave = tid >> 6, lane = tid & 63;
    if (lane == 0) {
#pragma unroll
        for (int i = 0; i < NSUM; ++i) partial[wave][i] = acc[i];
    }
    __syncthreads();
    if (tid < NSUM) {
        sums[tid] = (double)partial[0][tid] + (double)partial[1][tid]
                  + (double)partial[2][tid] + (double)partial[3][tid];
    }
    __syncthreads();
    if (tid != 0) return;

    // ---- per-batch scalar math in fp64 ----
    const double M   = sums[0];
    const double Mep = M + 1e-8;
    double Sp[3] = { sums[1], sums[2], sums[3] };
    double St[3] = { sums[4], sums[5], sums[6] };
    double pc[3] = { Sp[0] / Mep, Sp[1] / Mep, Sp[2] / Mep };
    double tc[3] = { St[0] / Mep, St[1] / Mep, St[2] / Mep };
    const double Qp = sums[7], Qt = sums[8];
    double Cpt[3][3];
    for (int i = 0; i < 3; ++i)
        for (int j = 0; j < 3; ++j) Cpt[i][j] = sums[9 + i * 3 + j];
    const double S2 = sums[18];
    double S2p[3] = { sums[19], sums[20], sums[21] };
    double S2t[3] = { sums[22], sums[23], sums[24] };
    double C2[3][3];
    for (int i = 0; i < 3; ++i)
        for (int j = 0; j < 3; ++j) C2[i][j] = sums[25 + i * 3 + j];

    // H[i][j] = sum m^2 (p-pc)_i (t-tc)_j   (reference weights both operands by m)
    double H[3][3];
    for (int i = 0; i < 3; ++i)
        for (int j = 0; j < 3; ++j)
            H[i][j] = C2[i][j] - pc[i] * S2t[j] - tc[j] * S2p[i] + pc[i] * tc[j] * S2;

    // Horn quaternion method: N matrix from S_ab = H[a][b]
    const double Sxx = H[0][0], Sxy = H[0][1], Sxz = H[0][2];
    const double Syx = H[1][0], Syy = H[1][1], Syz = H[1][2];
    const double Szx = H[2][0], Szy = H[2][1], Szz = H[2][2];
    double A[4][4] = {
        { Sxx + Syy + Szz, Syz - Szy,        Szx - Sxz,        Sxy - Syx },
        { Syz - Szy,       Sxx - Syy - Szz,  Sxy + Syx,        Szx + Sxz },
        { Szx - Sxz,       Sxy + Syx,       -Sxx + Syy - Szz,  Syz + Szy },
        { Sxy - Syx,       Szx + Sxz,        Syz + Szy,       -Sxx - Syy + Szz }
    };
    double Vm[4][4] = { {1,0,0,0},{0,1,0,0},{0,0,1,0},{0,0,0,1} };

    // Jacobi eigensolver (4x4 symmetric), 16 sweeps
    for (int sweep = 0; sweep < 16; ++sweep) {
        for (int p = 0; p < 3; ++p) {
            for (int q = p + 1; q < 4; ++q) {
                const double apq = A[p][q];
                if (fabs(apq) < 1e-30) continue;
                const double theta = (A[q][q] - A[p][p]) / (2.0 * apq);
                const double tt = (theta >= 0.0 ? 1.0 : -1.0)
                                / (fabs(theta) + sqrt(theta * theta + 1.0));
                const double c = 1.0 / sqrt(tt * tt + 1.0);
                const double s = tt * c;
                for (int k = 0; k < 4; ++k) {
                    const double akp = A[k][p], akq = A[k][q];
                    A[k][p] = c * akp - s * akq;
                    A[k][q] = s * akp + c * akq;
                }
                for (int k = 0; k < 4; ++k) {
                    const double apk = A[p][k], aqk = A[q][k];
                    A[p][k] = c * apk - s * aqk;
                    A[q][k] = s * apk + c * aqk;
                }
                for (int k = 0; k < 4; ++k) {
                    const double vkp = Vm[k][p], vkq = Vm[k][q];
                    Vm[k][p] = c * vkp - s * vkq;
                    Vm[k][q] = s * vkp + c * vkq;
                }
            }
        }
    }
    int best = 0;
    for (int i = 1; i < 4; ++i) if (A[i][i] > A[best][best]) best = i;
    double q0 = Vm[0][best], qx = Vm[1][best], qy = Vm[2][best], qz = Vm[3][best];
    const double nq = sqrt(q0*q0 + qx*qx + qy*qy + qz*qz);
    q0 /= nq; qx /= nq; qy /= nq; qz /= nq;

    double R[3][3] = {
        { 1 - 2*(qy*qy + qz*qz), 2*(qx*qy - qz*q0),     2*(qx*qz + qy*q0) },
        { 2*(qx*qy + qz*q0),     1 - 2*(qx*qx + qz*qz), 2*(qy*qz - qx*q0) },
        { 2*(qx*qz - qy*q0),     2*(qy*qz + qx*q0),     1 - 2*(qx*qx + qy*qy) }
    };

    // G[i][j] = sum m (t-tc)_i (p-pc)_j
    double cross = 0.0;
    for (int i = 0; i < 3; ++i)
        for (int j = 0; j < 3; ++j) {
            const double Gij = Cpt[j][i] - tc[i] * Sp[j] - pc[j] * St[i]
                             + tc[i] * pc[j] * M;
            cross += R[i][j] * Gij;
        }

    const double Qpc = Qp - 2.0*(pc[0]*Sp[0] + pc[1]*Sp[1] + pc[2]*Sp[2])
                     + (pc[0]*pc[0] + pc[1]*pc[1] + pc[2]*pc[2]) * M;
    const double Qtc = Qt - 2.0*(tc[0]*St[0] + tc[1]*St[1] + tc[2]*St[2])
                     + (tc[0]*tc[0] + tc[1]*tc[1] + tc[2]*tc[2]) * M;
    double D = Qpc + Qtc - 2.0 * cross;
    if (D < 0.0) D = 0.0;
    ws[b] = (float)sqrt(D / Mep);
}

__global__ __launch_bounds__(256) void mean_kernel(const float* __restrict__ ws,
                                                   float* __restrict__ out)
{
    const int tid = threadIdx.x;
    float v = ws[tid];
#pragma unroll
    for (int off = 32; off > 0; off >>= 1) v += __shfl_down(v, off, 64);
    __shared__ float part[4];
    if ((tid & 63) == 0) part[tid >> 6] = v;
    __syncthreads();
    if (tid == 0)
        out[0] = (part[0] + part[1] + part[2] + part[3]) * (1.0f / (float)NBATCH);
}

extern "C" void kernel_launch(void* const* d_in, const int* in_sizes, int n_in,
                              void* d_out, int out_size, void* d_ws, size_t ws_size,
                              hipStream_t stream) {
    const float* pred  = (const float*)d_in[0];
    const float* truec = (const float*)d_in[1];
    const float* mask  = (const float*)d_in[2];
    float* out = (float*)d_out;
    float* ws  = (float*)d_ws;

    rmsd_batch_kernel<<<NBATCH, 256, 0, stream>>>(pred, truec, mask, ws);
    mean_kernel<<<1, 256, 0, stream>>>(ws, out);
}